// Round 7
// baseline (290.267 us; speedup 1.0000x reference)
//
#include <hip/hip_runtime.h>
#include <hip/hip_bf16.h>
#include <math.h>

#define B_DIM 16
#define T_DIM 4096
#define D_DIM 512
#define R_DIM 256

#define TM 64           // rows (t) per block
#define LDPA 536        // LDS row pitch in bf16 (1072 B): b128 reads+writes at bank minimum
#define NKS (D_DIM/32)  // 16 k-steps of 32
#define THREADS 512     // 8 waves; wave owns 32 cols -> acc[4][2] = 32 AGPR
#define ASIZE (TM * LDPA * 2)   // 68608 B per matrix (hi or lo)

typedef __bf16 bf16x8 __attribute__((ext_vector_type(8)));
typedef float floatx4 __attribute__((ext_vector_type(4)));

// Replicate np.linspace(0, T-1, R).astype(int64) bit-exactly.
__device__ __forceinline__ int landmark_of(int r) {
    if (r >= 255) return 4095;
    const double step = 4095.0 / 255.0;
    return (int)((double)r * step);   // trunc toward zero == astype(int64)
}

__device__ __forceinline__ void split_bf16(float x, __bf16& h, __bf16& l) {
    h = (__bf16)x;
    l = (__bf16)(x - (float)h);
}

// ---- prep: normalized landmark rows of z, split hi/lo, written in MFMA
// FRAGMENT order: Kf[b][ks 0..15][rb 0..15][lam 0..63][8 bf16], where
// lam = col_octet*16 + (r&15) and element j is B[r = rb*16 + (r&15)][k =
// ks*32 + col_octet*8 + j]. ----
__global__ void nystrom_prep_kernel(const float* __restrict__ z,
                                    __bf16* __restrict__ Khi, __bf16* __restrict__ Klo) {
    int blk = blockIdx.x;
    int b = blk >> 8;
    int r = blk & 255;
    int lane = threadIdx.x;            // 64 threads
    int lm = landmark_of(r);
    const float* src = z + ((size_t)b * T_DIM + lm) * D_DIM + lane * 8;
    float4 v0 = ((const float4*)src)[0];
    float4 v1 = ((const float4*)src)[1];
    float ss = v0.x*v0.x + v0.y*v0.y + v0.z*v0.z + v0.w*v0.w
             + v1.x*v1.x + v1.y*v1.y + v1.z*v1.z + v1.w*v1.w;
    #pragma unroll
    for (int off = 1; off < 64; off <<= 1) ss += __shfl_xor(ss, off, 64);
    float inv = 1.0f / fmaxf(sqrtf(ss), 1e-12f);
    float q[8] = {v0.x*inv, v0.y*inv, v0.z*inv, v0.w*inv,
                  v1.x*inv, v1.y*inv, v1.z*inv, v1.w*inv};
    bf16x8 oh, ol;
    #pragma unroll
    for (int j = 0; j < 8; j++) { __bf16 h, l; split_bf16(q[j], h, l); oh[j] = h; ol[j] = l; }
    size_t dst = ((((size_t)b * NKS + (lane >> 2)) * 16 + (r >> 4)) * 64
                  + (size_t)(lane & 3) * 16 + (r & 15)) * 8;
    *(bf16x8*)(Khi + dst) = oh;
    *(bf16x8*)(Klo + dst) = ol;
}

// Full 16-step MFMA chain, no barriers, compile-time NACT live chunks.
// Straight-line: compiler hoists B global loads across steps (counted vmcnt)
// and interleaves with MFMAs; waves desynchronize freely.
template<int NACT>
__device__ __forceinline__ void kchain(const __bf16* __restrict__ Ash,
                                       const __bf16* __restrict__ Asl,
                                       const __bf16* __restrict__ khb,
                                       const __bf16* __restrict__ klb,
                                       int quad, int ln, floatx4 (&acc)[4][2]) {
    #pragma unroll
    for (int s = 0; s < 16; s++) {
        const __bf16* khp = khb + s * 8192;
        const __bf16* klp = klb + s * 8192;
        bf16x8 bh[NACT], bl[NACT];
        #pragma unroll
        for (int ni = 0; ni < NACT; ni++) {
            bh[ni] = *(const bf16x8*)(khp + ni * 4096);   // chunk stride: 8 rb * 512
            bl[ni] = *(const bf16x8*)(klp + ni * 4096);
        }
        const int koff = s * 32 + quad * 8;
        __builtin_amdgcn_s_setprio(1);
        #pragma unroll
        for (int mi = 0; mi < 4; mi++) {
            bf16x8 afh = *(const bf16x8*)&Ash[(mi * 16 + ln) * LDPA + koff];
            bf16x8 afl = *(const bf16x8*)&Asl[(mi * 16 + ln) * LDPA + koff];
            #pragma unroll
            for (int ni = 0; ni < NACT; ni++) {
                acc[mi][ni] = __builtin_amdgcn_mfma_f32_16x16x32_bf16(afh, bh[ni], acc[mi][ni], 0, 0, 0);
                acc[mi][ni] = __builtin_amdgcn_mfma_f32_16x16x32_bf16(afh, bl[ni], acc[mi][ni], 0, 0, 0);
                acc[mi][ni] = __builtin_amdgcn_mfma_f32_16x16x32_bf16(afl, bh[ni], acc[mi][ni], 0, 0, 0);
            }
        }
        __builtin_amdgcn_s_setprio(0);
    }
}

// ---- main: MEGA shape. Whole 64x512 A-tile staged ONCE (16 float4/thread
// issued upfront = 131 KB/block of z in flight -> stage runs at BW, not
// latency), ONE barrier, then barrier-free 16-step MFMA chain with B from
// global. 137 KB LDS -> 1 block/CU (occupancy sacrificed deliberately;
// R6 proved TLP is not the lever). Causal chunk skip kept. ----
__global__ __launch_bounds__(THREADS, 2)
void nystrom_main_kernel(const float* __restrict__ z,
                         const __bf16* __restrict__ Khi, const __bf16* __restrict__ Klo,
                         const float* __restrict__ gw, const float* __restrict__ ta,
                         float* __restrict__ out) {
    __shared__ __attribute__((aligned(16))) char smem[2 * ASIZE];   // 137216 B
    __shared__ int   lmtab[R_DIM];
    __shared__ float elmtab[R_DIM];

    float* red    = (float*)(smem);           // 2048 B (epilogue alias; post-barrier)
    float* rnormp = (float*)(smem + 2048);    // 256 B
    float* rinvp  = (float*)(smem + 2304);    // 256 B
    float* rspart = (float*)(smem + 2560);    // 8*64*4 = 2048 B

    const int tid  = threadIdx.x;
    const int bid  = blockIdx.x;
    const int b    = bid & 15;                // t-tile varies fastest across CUs
    const int t0   = (bid >> 4) * TM;
    const int lane = tid & 63;
    const int wv   = tid >> 6;                // 0..7
    const int quad = lane >> 4;
    const int ln   = lane & 15;

    // --- scalars ---
    float g0 = gw[0], g1 = gw[1], g2 = gw[2];
    float gm = fmaxf(g0, fmaxf(g1, g2));
    float e0 = expf(g0 - gm), e1 = expf(g1 - gm), e2 = expf(g2 - gm);
    float esum = e0 + e1 + e2;
    float al0 = e0 / esum, al1 = e1 / esum, al2 = e2 / esum;
    float ax = ta[0];
    float a_td = (ax > 20.f) ? ax : log1pf(expf(ax));

    if (tid < R_DIM) {
        int lm = landmark_of(tid);
        lmtab[tid] = lm;
        elmtab[tid] = expf(a_td * (float)lm * (1.0f / 4096.0f));
    }

    // --- causal chunk-activity: wave's ni-chunk covers cols
    // r = ni*128 + wv*16 + [0,16). Live iff min landmark < t0+TM-1. ---
    int nact = 0;
    #pragma unroll
    for (int ni = 0; ni < 2; ni++)
        if (landmark_of(ni * 128 + wv * 16) < t0 + TM - 1) nact = ni + 1;

    // staging map: 8 threads per row, 64 consecutive cols each
    const int srowA = tid >> 3;
    const int scolA = (tid & 7) * 64;
    const float* zrow = z + ((size_t)b * T_DIM + (t0 + srowA)) * D_DIM + scolA;

    // B fragment base: rb = ni*8 + wv; per (s,ni) offset = s*8192 + ni*4096
    const size_t kfoff = (size_t)b * (NKS * 16 * 64 * 8)
                       + (size_t)wv * 512 + (size_t)lane * 8;
    const __bf16* khb = Khi + kfoff;
    const __bf16* klb = Klo + kfoff;

    floatx4 acc[4][2];
    #pragma unroll
    for (int i = 0; i < 4; i++)
        #pragma unroll
        for (int j = 0; j < 2; j++) acc[i][j] = (floatx4){0.f, 0.f, 0.f, 0.f};

    // ---- stage: issue ALL 16 float4 loads upfront (deep MLP), then
    // convert + LDS-write the whole 64x512 tile. ----
    float4 az[16];
    #pragma unroll
    for (int j = 0; j < 16; j++) az[j] = ((const float4*)zrow)[j];

    float ssq = 0.0f;
    {
        __bf16* Ash = (__bf16*)(smem);
        __bf16* Asl = (__bf16*)(smem + ASIZE);
        #pragma unroll
        for (int c = 0; c < 8; c++) {          // one bf16x8 = 2 float4
            float av[8] = {az[2*c].x, az[2*c].y, az[2*c].z, az[2*c].w,
                           az[2*c+1].x, az[2*c+1].y, az[2*c+1].z, az[2*c+1].w};
            #pragma unroll
            for (int j = 0; j < 8; j++) ssq += av[j] * av[j];
            bf16x8 ph, pl;
            #pragma unroll
            for (int j = 0; j < 8; j++) { __bf16 h, l; split_bf16(av[j], h, l); ph[j] = h; pl[j] = l; }
            *(bf16x8*)&Ash[srowA * LDPA + scolA + c * 8] = ph;
            *(bf16x8*)&Asl[srowA * LDPA + scolA + c * 8] = pl;
        }
    }
    __syncthreads();   // the ONE staging barrier

    // ---- barrier-free MFMA chain over all 512 k ----
    {
        const __bf16* Ash = (const __bf16*)(smem);
        const __bf16* Asl = (const __bf16*)(smem + ASIZE);
        switch (nact) {
            case 2: kchain<2>(Ash, Asl, khb, klb, quad, ln, acc); break;
            case 1: kchain<1>(Ash, Asl, khb, klb, quad, ln, acc); break;
            default: break;   // fully-masked wave: nothing to compute
        }
    }
    __syncthreads();   // all waves done reading A before epilogue aliases LDS

    // --- row norms: 8 partials per row ---
    red[tid] = ssq;
    __syncthreads();
    if (tid < TM) {
        float s = 0.f;
        #pragma unroll
        for (int j = 0; j < 8; j++) s += red[tid * 8 + j];
        rnormp[tid] = 1.0f / fmaxf(sqrtf(s), 1e-12f);
    }
    __syncthreads();

    // per-thread landmark columns (r = ni*128 + wv*16 + ln)
    int   lm_r[2];
    float elm_r[2];
    #pragma unroll
    for (int ni = 0; ni < 2; ni++) {
        int r = ni * 128 + wv * 16 + ln;
        lm_r[ni]  = lmtab[r];
        elm_r[ni] = elmtab[r];
    }

    // --- polynomial + mask + decay; row-sum reduce ---
    #pragma unroll
    for (int mi = 0; mi < 4; mi++) {
        #pragma unroll
        for (int reg = 0; reg < 4; reg++) {
            int row = mi * 16 + quad * 4 + reg;
            int t = t0 + row;
            float rn = rnormp[row];
            float e_t = __expf(-a_td * (float)t * (1.0f / 4096.0f));
            float s = 0.f;
            #pragma unroll
            for (int ni = 0; ni < 2; ni++) {
                float phi = 0.f;
                if (lm_r[ni] < t) {
                    float c  = acc[mi][ni][reg] * rn;
                    float c2 = c * c;
                    float P1 = 0.5f * (1.f + c);
                    float P2 = 0.5f * (3.f * c2 - 1.f);
                    float P3 = 0.5f * (5.f * c2 * c - 3.f * c);
                    float p  = al0 * P1 + al1 * P2 + al2 * P3;
                    phi = p * e_t * elm_r[ni];
                }
                acc[mi][ni][reg] = phi;
                s += phi;
            }
            #pragma unroll
            for (int off = 1; off < 16; off <<= 1) s += __shfl_xor(s, off, 64);
            if (ln == 0) rspart[wv * TM + row] = s;
        }
    }
    __syncthreads();
    if (tid < TM) {
        float rs = 0.f;
        #pragma unroll
        for (int w = 0; w < 8; w++) rs += rspart[w * TM + tid];
        rinvp[tid] = 1.0f / fmaxf(rs, 1e-6f);
    }
    __syncthreads();

    // --- store Phi + ones column ---
    float* ob = out + ((size_t)b * T_DIM + t0) * 257;
    #pragma unroll
    for (int mi = 0; mi < 4; mi++) {
        #pragma unroll
        for (int reg = 0; reg < 4; reg++) {
            int row = mi * 16 + quad * 4 + reg;
            float inv = rinvp[row];
            #pragma unroll
            for (int ni = 0; ni < 2; ni++) {
                int r = ni * 128 + wv * 16 + ln;
                ob[(size_t)row * 257 + r] = acc[mi][ni][reg] * inv;
            }
        }
    }
    if (tid < TM) ob[(size_t)tid * 257 + 256] = 1.0f;
}

extern "C" void kernel_launch(void* const* d_in, const int* in_sizes, int n_in,
                              void* d_out, int out_size, void* d_ws, size_t ws_size,
                              hipStream_t stream) {
    const float* z  = (const float*)d_in[0];
    const float* gw = (const float*)d_in[1];
    const float* ta = (const float*)d_in[2];
    float* out = (float*)d_out;
    __bf16* Khi = (__bf16*)d_ws;                                               // 4 MiB
    __bf16* Klo = (__bf16*)((char*)d_ws + (size_t)B_DIM * R_DIM * D_DIM * 2);  // +4 MiB

    nystrom_prep_kernel<<<dim3(B_DIM * R_DIM), 64, 0, stream>>>(z, Khi, Klo);
    nystrom_main_kernel<<<dim3((T_DIM / TM) * B_DIM), THREADS, 0, stream>>>(z, Khi, Klo, gw, ta, out);
}

// Round 8
// 262.083 us; speedup vs baseline: 1.1075x; 1.1075x over previous
//
#include <hip/hip_runtime.h>
#include <hip/hip_bf16.h>
#include <math.h>

#define B_DIM 16
#define T_DIM 4096
#define D_DIM 512
#define R_DIM 256

#define TM 64           // rows (t) per block
#define BK 64           // k-tile (2 MFMA k-steps of 32)
#define LDP 72          // LDS row pitch in bf16 (144 B): 2-way max on frag reads
#define NKS (D_DIM/32)  // 16 k-steps of 32
#define THREADS 512     // 8 waves; wave owns 32 cols -> acc[4][2] = 32 AGPR

typedef __bf16 bf16x8 __attribute__((ext_vector_type(8)));
typedef float floatx4 __attribute__((ext_vector_type(4)));

// Replicate np.linspace(0, T-1, R).astype(int64) bit-exactly.
__device__ __forceinline__ int landmark_of(int r) {
    if (r >= 255) return 4095;
    const double step = 4095.0 / 255.0;
    return (int)((double)r * step);   // trunc toward zero == astype(int64)
}

__device__ __forceinline__ void split_bf16(float x, __bf16& h, __bf16& l) {
    h = (__bf16)x;
    l = (__bf16)(x - (float)h);
}

// ---- prep: normalized landmark rows of z, split hi/lo, in MFMA fragment
// order Kf[b][ks][rb][lam][8], lam = col_octet*16 + (r&15). ----
__global__ void nystrom_prep_kernel(const float* __restrict__ z,
                                    __bf16* __restrict__ Khi, __bf16* __restrict__ Klo) {
    int blk = blockIdx.x;
    int b = blk >> 8;
    int r = blk & 255;
    int lane = threadIdx.x;            // 64 threads
    int lm = landmark_of(r);
    const float* src = z + ((size_t)b * T_DIM + lm) * D_DIM + lane * 8;
    float4 v0 = ((const float4*)src)[0];
    float4 v1 = ((const float4*)src)[1];
    float ss = v0.x*v0.x + v0.y*v0.y + v0.z*v0.z + v0.w*v0.w
             + v1.x*v1.x + v1.y*v1.y + v1.z*v1.z + v1.w*v1.w;
    #pragma unroll
    for (int off = 1; off < 64; off <<= 1) ss += __shfl_xor(ss, off, 64);
    float inv = 1.0f / fmaxf(sqrtf(ss), 1e-12f);
    float q[8] = {v0.x*inv, v0.y*inv, v0.z*inv, v0.w*inv,
                  v1.x*inv, v1.y*inv, v1.z*inv, v1.w*inv};
    bf16x8 oh, ol;
    #pragma unroll
    for (int j = 0; j < 8; j++) { __bf16 h, l; split_bf16(q[j], h, l); oh[j] = h; ol[j] = l; }
    size_t dst = ((((size_t)b * NKS + (lane >> 2)) * 16 + (r >> 4)) * 64
                  + (size_t)(lane & 3) * 16 + (r & 15)) * 8;
    *(bf16x8*)(Khi + dst) = oh;
    *(bf16x8*)(Klo + dst) = ol;
}

// load B fragments for k-step g into register arrays (static indexing)
template<int NACT>
__device__ __forceinline__ void ldB(const __bf16* __restrict__ khb,
                                    const __bf16* __restrict__ klb, int g,
                                    bf16x8 (&bh)[NACT], bf16x8 (&bl)[NACT]) {
    const __bf16* khp = khb + (size_t)g * 8192;
    const __bf16* klp = klb + (size_t)g * 8192;
    #pragma unroll
    for (int ni = 0; ni < NACT; ni++) {
        bh[ni] = *(const bf16x8*)(khp + ni * 4096);   // chunk stride: 8 rb * 512
        bl[ni] = *(const bf16x8*)(klp + ni * 4096);
    }
}

template<int NACT>
__device__ __forceinline__ void mfma_step(const __bf16* __restrict__ Ash,
                                          const __bf16* __restrict__ Asl,
                                          int koff, int ln,
                                          const bf16x8 (&bh)[NACT], const bf16x8 (&bl)[NACT],
                                          floatx4 (&acc)[4][2]) {
    __builtin_amdgcn_s_setprio(1);
    #pragma unroll
    for (int mi = 0; mi < 4; mi++) {
        bf16x8 afh = *(const bf16x8*)&Ash[(mi * 16 + ln) * LDP + koff];
        bf16x8 afl = *(const bf16x8*)&Asl[(mi * 16 + ln) * LDP + koff];
        #pragma unroll
        for (int ni = 0; ni < NACT; ni++) {
            acc[mi][ni] = __builtin_amdgcn_mfma_f32_16x16x32_bf16(afh, bh[ni], acc[mi][ni], 0, 0, 0);
            acc[mi][ni] = __builtin_amdgcn_mfma_f32_16x16x32_bf16(afh, bl[ni], acc[mi][ni], 0, 0, 0);
            acc[mi][ni] = __builtin_amdgcn_mfma_f32_16x16x32_bf16(afl, bh[ni], acc[mi][ni], 0, 0, 0);
        }
    }
    __builtin_amdgcn_s_setprio(0);
}

// convert 8 staged floats -> split bf16, write to A buffer `buf`
__device__ __forceinline__ void stageA(char* smem, int buf, int srowA, int scolA,
                                       const float4& z0, const float4& z1, float& ssq) {
    float av[8] = {z0.x,z0.y,z0.z,z0.w, z1.x,z1.y,z1.z,z1.w};
    #pragma unroll
    for (int j = 0; j < 8; j++) ssq += av[j] * av[j];
    bf16x8 ph, pl;
    #pragma unroll
    for (int j = 0; j < 8; j++) { __bf16 h, l; split_bf16(av[j], h, l); ph[j] = h; pl[j] = l; }
    __bf16* Ash = (__bf16*)(smem + buf * 18432);
    __bf16* Asl = (__bf16*)(smem + buf * 18432 + 9216);
    *(bf16x8*)&Ash[srowA * LDP + scolA] = ph;
    *(bf16x8*)&Asl[srowA * LDP + scolA] = pl;
}

// K-loop with B prefetched one k-step ahead (reg ping-pong Bc/Bn) and z
// prefetched two tiles ahead (zc/zn). 9 barriers total (1 prologue + 8).
template<int NACT>
__device__ __forceinline__ void kloop(const float* __restrict__ zrow,
                                      const __bf16* __restrict__ khb,
                                      const __bf16* __restrict__ klb,
                                      char* smem, int srowA, int scolA, int quad, int ln,
                                      floatx4 (&acc)[4][2], float& ssq) {
    bf16x8 bhc[NACT], blc[NACT], bhn[NACT], bln[NACT];
    ldB<NACT>(khb, klb, 0, bhc, blc);       // B(0), B(1) in flight across prologue
    ldB<NACT>(khb, klb, 1, bhn, bln);
    float4 zc0, zc1, zn0, zn1;
    {
        const float4* ap = (const float4*)zrow;
        float4 t0 = ap[0], t1 = ap[1];
        const float4* ap1 = (const float4*)(zrow + BK);   // tile 1 issued early
        zc0 = ap1[0]; zc1 = ap1[1];
        stageA(smem, 0, srowA, scolA, t0, t1, ssq);
    }
    __syncthreads();
    #pragma unroll 1
    for (int it = 0; it < 8; it++) {
        const int cur = it & 1;
        const __bf16* Ash = (const __bf16*)(smem + cur * 18432);
        const __bf16* Asl = (const __bf16*)(smem + cur * 18432 + 9216);
        if (it < 6) {   // z(it+2): in flight a full iteration
            const float4* ap = (const float4*)(zrow + (it + 2) * BK);
            zn0 = ap[0]; zn1 = ap[1];
        }
        mfma_step<NACT>(Ash, Asl, quad * 8,      ln, bhc, blc, acc);
        if (it < 7) ldB<NACT>(khb, klb, 2 * it + 2, bhc, blc);   // next iter s=0
        mfma_step<NACT>(Ash, Asl, 32 + quad * 8, ln, bhn, bln, acc);
        if (it < 7) ldB<NACT>(khb, klb, 2 * it + 3, bhn, bln);   // next iter s=1
        if (it < 7) {
            stageA(smem, cur ^ 1, srowA, scolA, zc0, zc1, ssq);  // tile it+1
            zc0 = zn0; zc1 = zn1;
        }
        __syncthreads();
    }
}

// fully-masked wave: stage + barriers only (identical barrier schedule)
__device__ __forceinline__ void kloop0(const float* __restrict__ zrow,
                                       char* smem, int srowA, int scolA, float& ssq) {
    float4 zc0, zc1, zn0, zn1;
    {
        const float4* ap = (const float4*)zrow;
        float4 t0 = ap[0], t1 = ap[1];
        const float4* ap1 = (const float4*)(zrow + BK);
        zc0 = ap1[0]; zc1 = ap1[1];
        stageA(smem, 0, srowA, scolA, t0, t1, ssq);
    }
    __syncthreads();
    #pragma unroll 1
    for (int it = 0; it < 8; it++) {
        if (it < 6) {
            const float4* ap = (const float4*)(zrow + (it + 2) * BK);
            zn0 = ap[0]; zn1 = ap[1];
        }
        if (it < 7) {
            stageA(smem, (it & 1) ^ 1, srowA, scolA, zc0, zc1, ssq);
            zc0 = zn0; zc1 = zn1;
        }
        __syncthreads();
    }
}

// ---- main: R6 skeleton (512 thr, 8 waves, dbuf A, 1 barrier/iter, causal
// chunk skip, balanced 1-D grid) + deep load pipelining: B fragments
// prefetched one k-step ahead in registers, z two tiles ahead. ----
__global__ __launch_bounds__(THREADS, 3)
void nystrom_main_kernel(const float* __restrict__ z,
                         const __bf16* __restrict__ Khi, const __bf16* __restrict__ Klo,
                         const float* __restrict__ gw, const float* __restrict__ ta,
                         float* __restrict__ out) {
    __shared__ __attribute__((aligned(16))) char smem[36864];
    __shared__ int   lmtab[R_DIM];
    __shared__ float elmtab[R_DIM];

    float* red    = (float*)(smem);           // 2048 B (epilogue alias, buf0)
    float* rnormp = (float*)(smem + 2048);    // 256 B
    float* rinvp  = (float*)(smem + 2304);    // 256 B
    float* rspart = (float*)(smem + 2560);    // 8*64*4 = 2048 B

    const int tid  = threadIdx.x;
    const int bid  = blockIdx.x;
    const int b    = bid & 15;                // t-tile varies fastest across CUs
    const int t0   = (bid >> 4) * TM;
    const int lane = tid & 63;
    const int wv   = tid >> 6;                // 0..7
    const int quad = lane >> 4;
    const int ln   = lane & 15;

    // --- scalars ---
    float g0 = gw[0], g1 = gw[1], g2 = gw[2];
    float gm = fmaxf(g0, fmaxf(g1, g2));
    float e0 = expf(g0 - gm), e1 = expf(g1 - gm), e2 = expf(g2 - gm);
    float esum = e0 + e1 + e2;
    float al0 = e0 / esum, al1 = e1 / esum, al2 = e2 / esum;
    float ax = ta[0];
    float a_td = (ax > 20.f) ? ax : log1pf(expf(ax));

    if (tid < R_DIM) {
        int lm = landmark_of(tid);
        lmtab[tid] = lm;
        elmtab[tid] = expf(a_td * (float)lm * (1.0f / 4096.0f));
    }

    // causal chunk-activity: wave's ni-chunk covers cols r = ni*128+wv*16+[0,16)
    int nact = 0;
    #pragma unroll
    for (int ni = 0; ni < 2; ni++)
        if (landmark_of(ni * 128 + wv * 16) < t0 + TM - 1) nact = ni + 1;

    // staging map: 8 threads per row, 8 cols each (64x64 tile, 8 floats/thread)
    const int srowA = tid >> 3;
    const int scolA = (tid & 7) * 8;
    const float* zrow = z + ((size_t)b * T_DIM + (t0 + srowA)) * D_DIM + scolA;

    // B fragment base: rb = ni*8 + wv -> per (g,ni) offset = g*8192 + ni*4096
    const size_t kfoff = (size_t)b * (NKS * 16 * 64 * 8)
                       + (size_t)wv * 512 + (size_t)lane * 8;
    const __bf16* khb = Khi + kfoff;
    const __bf16* klb = Klo + kfoff;

    floatx4 acc[4][2];
    #pragma unroll
    for (int i = 0; i < 4; i++)
        #pragma unroll
        for (int j = 0; j < 2; j++) acc[i][j] = (floatx4){0.f, 0.f, 0.f, 0.f};
    float ssq = 0.0f;

    switch (nact) {
        case 2: kloop<2>(zrow, khb, klb, smem, srowA, scolA, quad, ln, acc, ssq); break;
        case 1: kloop<1>(zrow, khb, klb, smem, srowA, scolA, quad, ln, acc, ssq); break;
        default: kloop0(zrow, smem, srowA, scolA, ssq); break;
    }

    // --- row norms: 8 partials per row (epilogue scratch aliases buf0; last
    // iter read buf1 and the loop-end barrier ordered all reads) ---
    red[tid] = ssq;
    __syncthreads();
    if (tid < TM) {
        float s = 0.f;
        #pragma unroll
        for (int j = 0; j < 8; j++) s += red[tid * 8 + j];
        rnormp[tid] = 1.0f / fmaxf(sqrtf(s), 1e-12f);
    }
    __syncthreads();

    // per-thread landmark columns (r = ni*128 + wv*16 + ln)
    int   lm_r[2];
    float elm_r[2];
    #pragma unroll
    for (int ni = 0; ni < 2; ni++) {
        int r = ni * 128 + wv * 16 + ln;
        lm_r[ni]  = lmtab[r];
        elm_r[ni] = elmtab[r];
    }

    // --- polynomial + mask + decay; row-sum reduce ---
    #pragma unroll
    for (int mi = 0; mi < 4; mi++) {
        #pragma unroll
        for (int reg = 0; reg < 4; reg++) {
            int row = mi * 16 + quad * 4 + reg;
            int t = t0 + row;
            float rn = rnormp[row];
            float e_t = __expf(-a_td * (float)t * (1.0f / 4096.0f));
            float s = 0.f;
            #pragma unroll
            for (int ni = 0; ni < 2; ni++) {
                float phi = 0.f;
                if (lm_r[ni] < t) {
                    float c  = acc[mi][ni][reg] * rn;
                    float c2 = c * c;
                    float P1 = 0.5f * (1.f + c);
                    float P2 = 0.5f * (3.f * c2 - 1.f);
                    float P3 = 0.5f * (5.f * c2 * c - 3.f * c);
                    float p  = al0 * P1 + al1 * P2 + al2 * P3;
                    phi = p * e_t * elm_r[ni];
                }
                acc[mi][ni][reg] = phi;
                s += phi;
            }
            #pragma unroll
            for (int off = 1; off < 16; off <<= 1) s += __shfl_xor(s, off, 64);
            if (ln == 0) rspart[wv * TM + row] = s;
        }
    }
    __syncthreads();
    if (tid < TM) {
        float rs = 0.f;
        #pragma unroll
        for (int w = 0; w < 8; w++) rs += rspart[w * TM + tid];
        rinvp[tid] = 1.0f / fmaxf(rs, 1e-6f);
    }
    __syncthreads();

    // --- store Phi + ones column ---
    float* ob = out + ((size_t)b * T_DIM + t0) * 257;
    #pragma unroll
    for (int mi = 0; mi < 4; mi++) {
        #pragma unroll
        for (int reg = 0; reg < 4; reg++) {
            int row = mi * 16 + quad * 4 + reg;
            float inv = rinvp[row];
            #pragma unroll
            for (int ni = 0; ni < 2; ni++) {
                int r = ni * 128 + wv * 16 + ln;
                ob[(size_t)row * 257 + r] = acc[mi][ni][reg] * inv;
            }
        }
    }
    if (tid < TM) ob[(size_t)tid * 257 + 256] = 1.0f;
}

extern "C" void kernel_launch(void* const* d_in, const int* in_sizes, int n_in,
                              void* d_out, int out_size, void* d_ws, size_t ws_size,
                              hipStream_t stream) {
    const float* z  = (const float*)d_in[0];
    const float* gw = (const float*)d_in[1];
    const float* ta = (const float*)d_in[2];
    float* out = (float*)d_out;
    __bf16* Khi = (__bf16*)d_ws;                                               // 4 MiB
    __bf16* Klo = (__bf16*)((char*)d_ws + (size_t)B_DIM * R_DIM * D_DIM * 2);  // +4 MiB

    nystrom_prep_kernel<<<dim3(B_DIM * R_DIM), 64, 0, stream>>>(z, Khi, Klo);
    nystrom_main_kernel<<<dim3((T_DIM / TM) * B_DIM), THREADS, 0, stream>>>(z, Khi, Klo, gw, ta, out);
}